// Round 1
// 270.734 us; speedup vs baseline: 1.0119x; 1.0119x over previous
//
#include <hip/hip_runtime.h>
#include <stdint.h>

#define D_EMB 1024
#define NBATCH 8
#define SEQ 2048
#define MTOT (NBATCH*SEQ)   // 16384

typedef __attribute__((ext_vector_type(8))) short short8;
typedef __attribute__((ext_vector_type(4))) float f32x4;

__device__ __forceinline__ ushort bf16r(float x) {
  union { float f; uint32_t u; } c; c.f = x;
  return (ushort)((c.u + 0x7fffu + ((c.u >> 16) & 1u)) >> 16);
}

// async 16B/lane global->LDS (LDS dest must be wave-uniform base + lane*16)
__device__ __forceinline__ void cp16(const ushort* g, ushort* l) {
  __builtin_amdgcn_global_load_lds(
      (const __attribute__((address_space(1))) void*)g,
      (__attribute__((address_space(3))) void*)l, 16, 0, 0);
}

// merged: blocks <4096: wave-per-row cvt x->bf16 + vw[row]=x.wv_eff+sc[1]
//         blocks >=4096: cvt Wattn rows 0..2047 -> bf16 (q,k weights)
__global__ __launch_bounds__(256) void cvt_all(
    const float4* __restrict__ x4, const float4* __restrict__ W4,
    const float4* __restrict__ wv4, const float* __restrict__ sc,
    ushort* __restrict__ xb, ushort* __restrict__ wqkb, float* __restrict__ vw) {
  int tid = threadIdx.x;
  if (blockIdx.x < 4096) {
    int wave = tid >> 6, lane = tid & 63;
    long row = (long)blockIdx.x * 4 + wave;
    const float4* xr = x4 + row * 256;
    ushort* xo = xb + row * D_EMB;
    float s = 0.f;
    #pragma unroll
    for (int i = 0; i < 4; i++) {
      int idx = lane + i * 64;
      float4 v = xr[idx];
      float4 w = wv4[idx];
      *(ushort4*)(xo + idx * 4) = make_ushort4(bf16r(v.x), bf16r(v.y), bf16r(v.z), bf16r(v.w));
      s += v.x * w.x + v.y * w.y + v.z * w.z + v.w * w.w;
    }
    #pragma unroll
    for (int off = 32; off; off >>= 1) s += __shfl_xor(s, off);
    if (lane == 0) vw[row] = s + sc[1];
  } else {
    long base = (long)(blockIdx.x - 4096) * 1024 + tid;   // in float4 units
    #pragma unroll
    for (int i = 0; i < 4; i++) {
      long idx = base + i * 256;
      float4 v = W4[idx];
      *(ushort4*)(wqkb + idx * 4) = make_ushort4(bf16r(v.x), bf16r(v.y), bf16r(v.z), bf16r(v.w));
    }
  }
}

// init: b0 zero w_eff, b1 zero wv_eff, b2 sc[0]=bp.Wfc+bfc, b3..34 zero num/den (32768 f32)
__global__ void init_kernel(const float* __restrict__ bp, const float* __restrict__ Wfc,
                            const float* __restrict__ bfc,
                            float* __restrict__ w_eff, float* __restrict__ wv_eff,
                            float* __restrict__ numden, float* __restrict__ sc) {
  int tid = threadIdx.x;
  int b = blockIdx.x;
  if (b == 0) { w_eff[tid] = 0.f; return; }
  if (b == 1) { wv_eff[tid] = 0.f; return; }
  if (b >= 3) { numden[(long)(b - 3) * 1024 + tid] = 0.f; return; }
  float v = bp[tid] * Wfc[tid];
  int lane = tid & 63, w = tid >> 6;
  #pragma unroll
  for (int off = 32; off; off >>= 1) v += __shfl_xor(v, off);
  __shared__ float red[16];
  if (lane == 0) red[w] = v;
  __syncthreads();
  if (tid == 0) {
    float s = 0.f;
    #pragma unroll
    for (int i = 0; i < 16; i++) s += red[i];
    sc[0] = s + bfc[0];
  }
}

// w_eff[c] += sum over 16-d-chunk of Wfc[d]*Wp[d,c]   grid(4,64)
__global__ void prep1(const float* __restrict__ Wp, const float* __restrict__ Wfc,
                      float* __restrict__ w_eff) {
  int c = blockIdx.x * 256 + threadIdx.x;
  int d0 = blockIdx.y * 16;
  float s = 0.f;
  #pragma unroll
  for (int d = d0; d < d0 + 16; d++) s += Wfc[d] * Wp[(long)d * D_EMB + c];
  atomicAdd(&w_eff[c], s);
}

// grid(4,65): by<64 -> wv_eff[d] += sum over 16-c-chunk of w_eff[c]*Wattn[2048+c, d]
//             by==64 (bx==0) -> sc[1] = sum_c battn[2048+c]*w_eff[c]
__global__ void prep2(const float* __restrict__ Wattn, const float* __restrict__ battn,
                      const float* __restrict__ w_eff, float* __restrict__ wv_eff,
                      float* __restrict__ sc) {
  int tid = threadIdx.x;
  if (blockIdx.y == 64) {
    if (blockIdx.x != 0) return;
    float v = 0.f;
    #pragma unroll
    for (int i = 0; i < 4; i++) { int c = tid + i * 256; v += battn[2048 + c] * w_eff[c]; }
    int lane = tid & 63, w = tid >> 6;
    #pragma unroll
    for (int off = 32; off; off >>= 1) v += __shfl_xor(v, off);
    __shared__ float red[4];
    if (lane == 0) red[w] = v;
    __syncthreads();
    if (tid == 0) sc[1] = red[0] + red[1] + red[2] + red[3];
    return;
  }
  int d = blockIdx.x * 256 + tid;
  int c0 = blockIdx.y * 16;
  float s = 0.f;
  #pragma unroll
  for (int c = c0; c < c0 + 16; c++) s += w_eff[c] * Wattn[(long)(2048 + c) * D_EMB + d];
  atomicAdd(&wv_eff[d], s);
}

// ---------------- NT GEMM: 256x256 tile, BK=64, deep-pipelined (T2+T3+T4+T5) ----------------
// 512 threads = 8 waves (2M x 4N), per-wave tile 128x64, acc 8x4 frags of 16x16x32 bf16 MFMA.
// LDS 128KiB: per operand 4 regions of 16KiB = [buf(2)][kkhalf(2)][256 rows][32 k], chunk-swizzled
//   cs = c ^ ((row>>1)&3)  (applied by pre-swizzling GLOBAL src; LDS dest stays linear for
//   global_load_lds; ds_read applies the same XOR) -> 2-way max bank aliasing (free, m136).
// Main loop: 2*NT super-phases; phase s computes region R(s)=(tile&1, kk) and stages (4x cp16)
//   the region R(s-1) with data for 2 K-tiles ahead. End-of-phase: s_waitcnt vmcnt(6) (counted,
//   never 0 until tail) + s_barrier. Data read at phase s was staged at s-3 -> retired by the
//   vmcnt(6) at end of s-1 (4 loads/phase). Tail (staging stopped): vmcnt 4 -> 0.
// FUSED=false: C[m,n] = bf16(scale*acc + bias[n])   (GEMM1 -> qk)
// FUSED=true : per-row partial softmax: num[m] += sum_n exp(scale*acc)*vw[n], den[m] += sum_n exp
template<bool FUSED, bool REMAP>
__global__ __launch_bounds__(512, 2) void gemm_nt(
    const ushort* __restrict__ A, long lda, long sAz,
    const ushort* __restrict__ B, long ldb, long sBz,
    ushort* __restrict__ C, long ldc,
    const float* __restrict__ bias, float scale, int K,
    const float* __restrict__ vw, float* __restrict__ num, float* __restrict__ den) {
  __shared__ __align__(16) ushort lds[65536];   // A: ushort[0,32768), B: [32768,65536)

  int bx, by, z;
  if (REMAP) {
    // GEMM1 grid (8,64): flat%8 = XCD (m09 round-robin). XCD k owns M-stripe by in [8k,8k+8).
    int f = (int)(blockIdx.x + 8u * blockIdx.y);
    int xcd = f & 7, g = f >> 3;
    bx = g & 7; by = xcd * 8 + (g >> 3); z = 0;
  } else {
    bx = blockIdx.x; by = blockIdx.y; z = blockIdx.z;
  }

  const ushort* Az = A + (long)z * sAz;
  const ushort* Bz = B + (long)z * sBz;
  long m0 = (long)by * 256, n0 = (long)bx * 256;
  int t = threadIdx.x;
  int wave = t >> 6, lane = t & 63;
  int r = lane & 15, q = lane >> 4;
  int wm = wave >> 2, wn = wave & 3;     // wave rows [wm*128,+128), cols [wn*64,+64)

  f32x4 acc[8][4] = {};

  // staging: thread owns slots t (rows 0..127) and t+512 (rows 128..255); 4 chunks of 16B/row.
  // global src chunk is pre-swizzled so linear LDS placement == swizzled layout.
  int srow0 = t >> 2, srow1 = srow0 + 128;
  int scs = t & 3;
  const ushort* pA0 = Az + (m0 + srow0) * lda + (long)((scs ^ ((srow0 >> 1) & 3)) * 8);
  const ushort* pA1 = Az + (m0 + srow1) * lda + (long)((scs ^ ((srow1 >> 1) & 3)) * 8);
  const ushort* pB0 = Bz + (n0 + srow0) * ldb + (long)((scs ^ ((srow0 >> 1) & 3)) * 8);
  const ushort* pB1 = Bz + (n0 + srow1) * ldb + (long)((scs ^ ((srow1 >> 1) & 3)) * 8);
  ushort* ldsA = lds;
  ushort* ldsB = lds + 32768;
  int d0 = t * 8, d1 = (t + 512) * 8;    // linear LDS dest (ushort units) within region

  // ds_read offsets (ushort units) within a region; logical k-chunk q stored at q^((row>>1)&3),
  // and (row>>1)&3 == (r>>1)&3 since wm*128 and fr*16 are 0 mod 4 after >>1.
  int swz8 = (q ^ ((r >> 1) & 3)) * 8;
  int offa = (wm * 128 + r) * 32 + swz8;
  int offb = (wn * 64 + r) * 32 + swz8;

  int NT = K >> 6;            // 64-wide K-tiles (=16 for K=1024)
  int SMAX = 2 * NT;          // 32-wide super-phases

#define STAGE(tile_, kk_) do { \
    long ko_ = (long)(tile_) * 64 + (long)(kk_) * 32; \
    int rg_ = (((tile_) & 1) * 2 + (kk_)) * 8192; \
    cp16(pA0 + ko_, ldsA + rg_ + d0); \
    cp16(pA1 + ko_, ldsA + rg_ + d1); \
    cp16(pB0 + ko_, ldsB + rg_ + d0); \
    cp16(pB1 + ko_, ldsB + rg_ + d1); \
  } while (0)

  // prologue: tile0 (both halves) + tile1 half0 = 12 loads/thread; wait first 4 (tile0.k0)
  STAGE(0, 0); STAGE(0, 1); STAGE(1, 0);
  asm volatile("s_waitcnt vmcnt(8)" ::: "memory");
  __builtin_amdgcn_s_barrier();

  #pragma unroll 4
  for (int s = 0; s < SMAX; ++s) {
    int reg = (((s >> 1) & 1) * 2 + (s & 1)) * 8192;   // R(s): buf=(tile&1), kk=(s&1)
    short8 af[8], bfr[4];
    #pragma unroll
    for (int fr = 0; fr < 8; fr++)
      af[fr] = *(const short8*)(ldsA + reg + offa + fr * 512);
    #pragma unroll
    for (int j = 0; j < 4; j++)
      bfr[j] = *(const short8*)(ldsB + reg + offb + j * 512);

    // stage into R(s-1) (read finished last phase, barrier-separated): tile (s+3)>>1, kk (s+3)&1
    int stile = (s + 3) >> 1;
    if (stile < NT) STAGE(stile, (s + 3) & 1);

    __builtin_amdgcn_s_barrier();
    asm volatile("s_waitcnt lgkmcnt(0)" ::: "memory");
    __builtin_amdgcn_s_setprio(1);
    #pragma unroll
    for (int fr = 0; fr < 8; fr++)
      #pragma unroll
      for (int j = 0; j < 4; j++)
        acc[fr][j] = __builtin_amdgcn_mfma_f32_16x16x32_bf16(af[fr], bfr[j], acc[fr][j], 0, 0, 0);
    __builtin_amdgcn_s_setprio(0);

    // counted vmcnt (T4): keep <=6 loads (1.5 phases) in flight; tail drains 4 -> 0.
    if (s < SMAX - 3)       asm volatile("s_waitcnt vmcnt(6)" ::: "memory");
    else if (s == SMAX - 3) asm volatile("s_waitcnt vmcnt(4)" ::: "memory");
    else if (s == SMAX - 2) asm volatile("s_waitcnt vmcnt(0)" ::: "memory");
    __builtin_amdgcn_s_barrier();
  }
#undef STAGE

  // C/D layout (verified): row = wm*128 + fr*16 + q*4 + rr, col = wn*64 + j*16 + r
  if (!FUSED) {
    #pragma unroll
    for (int fr = 0; fr < 8; fr++) {
      #pragma unroll
      for (int j = 0; j < 4; j++) {
        long col = n0 + wn * 64 + j * 16 + r;
        float bj = bias[col];
        #pragma unroll
        for (int rr = 0; rr < 4; rr++) {
          long row = m0 + wm * 128 + fr * 16 + q * 4 + rr;
          C[row * ldc + col] = bf16r(acc[fr][j][rr] * scale + bj);
        }
      }
    }
  } else {
    const float* vwz = vw + (long)z * SEQ + n0;
    float* numz = num + (long)z * SEQ + m0;
    float* denz = den + (long)z * SEQ + m0;
    float vwj[4];
    #pragma unroll
    for (int j = 0; j < 4; j++) vwj[j] = vwz[wn * 64 + j * 16 + r];
    #pragma unroll
    for (int fr = 0; fr < 8; fr++) {
      #pragma unroll
      for (int rr = 0; rr < 4; rr++) {
        float sn = 0.f, sd = 0.f;
        #pragma unroll
        for (int j = 0; j < 4; j++) {
          float e = __expf(acc[fr][j][rr] * scale);
          sd += e;
          sn += e * vwj[j];
        }
        #pragma unroll
        for (int off = 1; off < 16; off <<= 1) {
          sn += __shfl_xor(sn, off);
          sd += __shfl_xor(sd, off);
        }
        if (r == 0) {
          int row = wm * 128 + fr * 16 + q * 4 + rr;
          atomicAdd(&numz[row], sn);
          atomicAdd(&denz[row], sd);
        }
      }
    }
  }
}

// out[row] = num[row]/den[row] + c_eff
__global__ __launch_bounds__(256) void finalize(
    const float* __restrict__ num, const float* __restrict__ den,
    const float* __restrict__ sc, float* __restrict__ out) {
  long i = blockIdx.x * 256L + threadIdx.x;
  out[i] = num[i] / den[i] + sc[0];
}

extern "C" void kernel_launch(void* const* d_in, const int* in_sizes, int n_in,
                              void* d_out, int out_size, void* d_ws, size_t ws_size,
                              hipStream_t stream) {
  const float* x     = (const float*)d_in[0];
  const float* Wattn = (const float*)d_in[1];
  const float* battn = (const float*)d_in[2];
  const float* Wproj = (const float*)d_in[3];
  const float* bproj = (const float*)d_in[4];
  const float* Wfc   = (const float*)d_in[5];
  const float* bfc   = (const float*)d_in[6];
  float* out = (float*)d_out;

  // ws layout (bytes)
  const size_t OFF_XB    = 0;          // bf16 [16384][1024]  33554432
  const size_t OFF_WQKB  = 33554432;   // bf16 [2048][1024]    4194304
  const size_t OFF_QK    = 37748736;   // bf16 [16384][2048]  67108864
  const size_t OFF_NUM   = 104857600;  // f32  [16384]           65536
  const size_t OFF_DEN   = 104923136;  // f32  [16384]           65536
  const size_t OFF_VW    = 104988672;  // f32  [16384]           65536
  const size_t OFF_WEFF  = 105054208;  // f32  [1024]
  const size_t OFF_WVEFF = 105058304;  // f32  [1024]
  const size_t OFF_SC    = 105062400;  // f32  [2] {c_eff, vb_eff}
  const size_t NEED      = 105062408;
  if (ws_size < NEED) return;

  char* ws = (char*)d_ws;
  ushort* xb    = (ushort*)(ws + OFF_XB);
  ushort* wqkb  = (ushort*)(ws + OFF_WQKB);
  ushort* qk    = (ushort*)(ws + OFF_QK);
  float* num    = (float*)(ws + OFF_NUM);
  float* den    = (float*)(ws + OFF_DEN);
  float* vw     = (float*)(ws + OFF_VW);
  float* w_eff  = (float*)(ws + OFF_WEFF);
  float* wv_eff = (float*)(ws + OFF_WVEFF);
  float* sc     = (float*)(ws + OFF_SC);

  init_kernel<<<dim3(35), dim3(1024), 0, stream>>>(bproj, Wfc, bfc, w_eff, wv_eff, num, sc);
  prep1<<<dim3(4, 64), dim3(256), 0, stream>>>(Wproj, Wfc, w_eff);
  prep2<<<dim3(4, 65), dim3(256), 0, stream>>>(Wattn, battn, w_eff, wv_eff, sc);

  cvt_all<<<dim3(4096 + 512), dim3(256), 0, stream>>>(
      (const float4*)x, (const float4*)Wattn, (const float4*)wv_eff, sc, xb, wqkb, vw);

  // GEMM1 (REMAP=true): qk[m, n] = bf16( x[m,:] . Wattn[n,:] + battn[n] ), n in [0,2048)
  gemm_nt<false, true><<<dim3(8, 64, 1), dim3(512), 0, stream>>>(
      xb, (long)D_EMB, 0L, wqkb, (long)D_EMB, 0L,
      qk, 2048L, battn, 1.0f, D_EMB, nullptr, nullptr, nullptr);

  // GEMM2: fused num/den partial softmax sums (scale = 1/sqrt(1024))
  gemm_nt<true, false><<<dim3(8, 8, NBATCH), dim3(512), 0, stream>>>(
      qk, 2048L, (long)SEQ * 2048, qk + 1024, 2048L, (long)SEQ * 2048,
      nullptr, 0L, nullptr, 0.03125f, D_EMB, vw, num, den);

  finalize<<<dim3(64), dim3(256), 0, stream>>>(num, den, sc, out);
}